// Round 1
// baseline (360.857 us; speedup 1.0000x reference)
//
#include <hip/hip_runtime.h>

#define N_NODES 100000
#define N_EDGES 3200000
#define D 128

#define MT 64                         // GEMM M-tile rows
#define BSPAN 32                      // rows per gather bucket
#define NB 3125                       // N_NODES / BSPAN (exact)
#define CAP 1280                      // records per bucket (mean 1024, +8 sigma)
#define PBLOCKS 256
#define PCHUNK (N_EDGES / PBLOCKS)    // 12500 edges per partition block
#define OVF_CAP 8192

// ws layout (bytes)
#define SUP_OFF     0ULL                               // bf16 support: 25,600,000
#define RECS_OFF    25600000ULL                        // NB*CAP*8 = 32,000,000
#define TAILS_OFF   (RECS_OFF + (size_t)NB * CAP * 8)  // NB ints
#define OVFCNT_OFF  (TAILS_OFF + (size_t)NB * 4)       // 1 int (contiguous)
#define OVF_OFF     ((OVFCNT_OFF + 15) & ~15ULL)
#define WS_NEED     (OVF_OFF + (size_t)OVF_CAP * 12)

typedef short short8 __attribute__((ext_vector_type(8)));
typedef float floatx4 __attribute__((ext_vector_type(4)));
typedef unsigned short ushort8v __attribute__((ext_vector_type(8)));

__device__ inline ushort f2bf(float f) {
  uint u = __float_as_uint(f);
  u += 0x7FFF + ((u >> 16) & 1);   // RNE
  return (ushort)(u >> 16);
}
__device__ inline float bf_lo(uint b) { return __uint_as_float(b << 16); }
__device__ inline float bf_hi(uint b) { return __uint_as_float(b & 0xFFFF0000u); }

// ---------------------------------------------------------------------------
// Kernel A: support(bf16) = x @ W + bias via MFMA 16x16x32 bf16.
// Block = 256 thr = 4 waves; 64-row M-tile; W transposed to LDS (WT[n][k]).
// ---------------------------------------------------------------------------
#define LSTR 136   // LDS row stride in shorts (16B-aligned, breaks pow2)

__global__ __launch_bounds__(256) void gcn_gemm_mfma(
    const float* __restrict__ x, const float* __restrict__ W,
    const float* __restrict__ bias, ushort* __restrict__ support, int M) {
  __shared__ ushort WT[D * LSTR];      // 34816 B, WT[n][k]
  __shared__ ushort XT[MT * LSTR];     // 17408 B, XT[m][k]; reused for repack

  const int t = threadIdx.x;
  const int w = t >> 6;
  const int lane = t & 63;
  const int quad = lane >> 4;
  const int l16 = lane & 15;
  const int row0 = blockIdx.x * MT;

  // stage W (row-major [k][n] fp32) -> WT[n][k] bf16 (transpose)
  for (int i = t * 4; i < D * D; i += 1024) {
    const int k = i >> 7, n = i & 127;
    const float4 wv = *(const float4*)&W[i];
    WT[(n + 0) * LSTR + k] = f2bf(wv.x);
    WT[(n + 1) * LSTR + k] = f2bf(wv.y);
    WT[(n + 2) * LSTR + k] = f2bf(wv.z);
    WT[(n + 3) * LSTR + k] = f2bf(wv.w);
  }
  // stage x rows -> XT[m][k] bf16 (zero-pad past M)
  for (int i = t * 4; i < MT * D; i += 1024) {
    const int m = i >> 7, k = i & 127;
    const int r = row0 + m;
    float4 xv = make_float4(0.f, 0.f, 0.f, 0.f);
    if (r < M) xv = *(const float4*)&x[(size_t)r * D + k];
    ushort4 pv;
    pv.x = f2bf(xv.x); pv.y = f2bf(xv.y); pv.z = f2bf(xv.z); pv.w = f2bf(xv.w);
    *(ushort4*)&XT[m * LSTR + k] = pv;
  }
  __syncthreads();

  floatx4 acc[8];
#pragma unroll
  for (int nt = 0; nt < 8; nt++) acc[nt] = (floatx4)0.f;

#pragma unroll
  for (int kc = 0; kc < 4; kc++) {
    const short8 a = *(const short8*)&XT[(w * 16 + l16) * LSTR + kc * 32 + quad * 8];
#pragma unroll
    for (int nt = 0; nt < 8; nt++) {
      const short8 b = *(const short8*)&WT[(nt * 16 + l16) * LSTR + kc * 32 + quad * 8];
      acc[nt] = __builtin_amdgcn_mfma_f32_16x16x32_bf16(a, b, acc[nt], 0, 0, 0);
    }
  }

  float bs[8];
#pragma unroll
  for (int nt = 0; nt < 8; nt++) bs[nt] = bias[nt * 16 + l16];

  __syncthreads();  // done reading XT as input tile
  // repack D into XT (row-major, stride LSTR) for coalesced writeout
#pragma unroll
  for (int nt = 0; nt < 8; nt++)
#pragma unroll
    for (int r = 0; r < 4; r++)
      XT[(w * 16 + quad * 4 + r) * LSTR + nt * 16 + l16] = f2bf(acc[nt][r] + bs[nt]);
  __syncthreads();

  for (int i = t * 8; i < MT * D; i += 2048) {
    const int m = i >> 7, k = i & 127;
    const int r = row0 + m;
    if (r < M)
      *(ushort8v*)&support[(size_t)r * D + k] = *(const ushort8v*)&XT[m * LSTR + k];
  }
}

// ---------------------------------------------------------------------------
// Partition: block-local binning -> contiguous per-block runs in row buckets.
// ---------------------------------------------------------------------------
__global__ __launch_bounds__(1024) void partition_kernel(
    const int* __restrict__ erow, const int* __restrict__ ecol,
    const float* __restrict__ eval, int* __restrict__ tails,
    int2* __restrict__ recs, int* __restrict__ ovf_cnt,
    int3* __restrict__ ovf) {
  __shared__ int cnt[NB];
  __shared__ int cursor[NB];
  const int t = threadIdx.x;
  for (int i = t; i < NB; i += 1024) cnt[i] = 0;
  __syncthreads();

  const int e0 = blockIdx.x * PCHUNK;
  for (int e = e0 + t; e < e0 + PCHUNK; e += 1024)
    atomicAdd(&cnt[erow[e] >> 5], 1);
  __syncthreads();

  for (int i = t; i < NB; i += 1024) {
    const int c = cnt[i];
    cursor[i] = (c > 0) ? atomicAdd(&tails[i], c) : 0;
  }
  __syncthreads();

  for (int e = e0 + t; e < e0 + PCHUNK; e += 1024) {
    const int row = erow[e];
    const int b = row >> 5;
    const int pos = atomicAdd(&cursor[b], 1);
    const int col = ecol[e];
    const int vb = __float_as_int(eval[e]);
    if (pos < CAP) {
      recs[(size_t)b * CAP + pos] = make_int2(col | ((row & 31) << 20), vb);
    } else {
      const int oi = atomicAdd(ovf_cnt, 1);
      if (oi < OVF_CAP) ovf[oi] = make_int3(row, col, vb);
    }
  }
}

// ---------------------------------------------------------------------------
// Fused bin+gather: block = one 32-row bucket (3125 blocks -> full occupancy).
//  1) records cached in registers; bin into per-row order in LDS
//  2) wave w owns rows w*8..+7; QUARTER-WAVE per record (4 records/iter):
//     lane owns 8 cols (uint4 = 16 B dwordx4), float8 register acc, groups
//     combined via shfl_xor(16|32); 512 B row written once by lanes 0-15.
// ---------------------------------------------------------------------------
__global__ __launch_bounds__(256, 8) void bucket_gather(
    const ushort* __restrict__ sup, const int* __restrict__ tails,
    const int2* __restrict__ recs, float* __restrict__ out) {
  __shared__ int2 lrec[CAP];            // 10 KB
  __shared__ int rcnt[BSPAN];
  __shared__ int rstart[BSPAN];
  __shared__ int rend[BSPAN];
  __shared__ int rpos[BSPAN];

  const int bi = blockIdx.x;
  const int t = threadIdx.x;
  const int n = min(tails[bi], CAP);
  const int2* __restrict__ gbase = recs + (size_t)bi * CAP;

  if (t < BSPAN) rcnt[t] = 0;
  __syncthreads();

  // cache this thread's records (<= ceil(CAP/256) = 5)
  int2 rcache[5];
  int nr = 0;
  for (int i = t; i < n; i += 256) rcache[nr++] = gbase[i];

  for (int j = 0; j < nr; j++) atomicAdd(&rcnt[rcache[j].x >> 20], 1);
  __syncthreads();

  if (t < BSPAN) {
    const int c = rcnt[t];
    int v = c;
#pragma unroll
    for (int off = 1; off < BSPAN; off <<= 1) {
      const int u = __shfl_up(v, off);
      if (t >= off) v += u;
    }
    rend[t] = v;
    rstart[t] = v - c;
    rpos[t] = v - c;
  }
  __syncthreads();

  for (int j = 0; j < nr; j++) {
    const int2 rc = rcache[j];
    const int p = atomicAdd(&rpos[rc.x >> 20], 1);
    lrec[p] = make_int2((rc.x & 0xFFFFF) << 8, rc.y);  // byte offset into sup
  }
  __syncthreads();

  const int lane = t & 63;
  const int w = t >> 6;
  const int g = lane >> 4;        // group index: which record of the quad
  const int gl = lane & 15;       // owns cols 8*gl .. 8*gl+7 (16 B)
  const char* __restrict__ supb = (const char*)sup;

  for (int j = 0; j < 8; j++) {
    const int rr = w * 8 + j;
    const int s = rstart[rr];
    const int e = rend[rr];
    float4 acc0 = make_float4(0.f, 0.f, 0.f, 0.f);
    float4 acc1 = make_float4(0.f, 0.f, 0.f, 0.f);
#pragma unroll 2
    for (int i = s; i < e; i += 4) {
      const int idx = i + g;
      const int2 rc = lrec[min(idx, CAP - 1)];
      const bool valid = idx < e;
      const int coff = valid ? rc.x : 0;
      const float val = valid ? __int_as_float(rc.y) : 0.f;
      const uint4 b = *(const uint4*)(supb + coff + gl * 16);
      acc0.x += val * bf_lo(b.x);
      acc0.y += val * bf_hi(b.x);
      acc0.z += val * bf_lo(b.y);
      acc0.w += val * bf_hi(b.y);
      acc1.x += val * bf_lo(b.z);
      acc1.y += val * bf_hi(b.z);
      acc1.z += val * bf_lo(b.w);
      acc1.w += val * bf_hi(b.w);
    }
#pragma unroll
    for (int off = 16; off <= 32; off <<= 1) {
      acc0.x += __shfl_xor(acc0.x, off);
      acc0.y += __shfl_xor(acc0.y, off);
      acc0.z += __shfl_xor(acc0.z, off);
      acc0.w += __shfl_xor(acc0.w, off);
      acc1.x += __shfl_xor(acc1.x, off);
      acc1.y += __shfl_xor(acc1.y, off);
      acc1.z += __shfl_xor(acc1.z, off);
      acc1.w += __shfl_xor(acc1.w, off);
    }
    const int row = bi * BSPAN + rr;
    if (g == 0 && row < N_NODES) {
      *(float4*)&out[(size_t)row * D + gl * 8] = acc0;
      *(float4*)&out[(size_t)row * D + gl * 8 + 4] = acc1;
    }
  }
}

// Overflow apply (expected n == 0; formal safety net). Runs AFTER gather.
__global__ __launch_bounds__(256) void ovf_apply(
    const int* __restrict__ ovf_cnt, const int3* __restrict__ ovf,
    const ushort* __restrict__ sup, float* __restrict__ out) {
  const int tid = blockIdx.x * 256 + threadIdx.x;
  const int e = tid >> 5;
  const int n = min(*ovf_cnt, OVF_CAP);
  if (e >= n) return;
  const int3 rec = ovf[e];
  const float val = __int_as_float(rec.z);
  const int j = (tid & 31) * 4;
#pragma unroll
  for (int k = 0; k < 4; k++) {
    const float f = __uint_as_float(((uint)sup[(size_t)rec.y * D + j + k]) << 16);
    unsafeAtomicAdd(&out[(size_t)rec.x * D + j + k], val * f);
  }
}

// Fallback (atomic path, bf16 support) if ws is too small.
__global__ __launch_bounds__(256) void gcn_spmm_atomic(
    const ushort* __restrict__ sup, const float* __restrict__ edge_val,
    const int* __restrict__ edge_row, const int* __restrict__ edge_col,
    float* __restrict__ out) {
  const long long tid = (long long)blockIdx.x * blockDim.x + threadIdx.x;
  const int e = (int)(tid >> 5);
  if (e >= N_EDGES) return;
  const int j = ((int)tid & 31) * 4;
  const int col = edge_col[e];
  const int row = edge_row[e];
  const float val = edge_val[e];
#pragma unroll
  for (int k = 0; k < 4; k++) {
    const float f = __uint_as_float(((uint)sup[(size_t)col * D + j + k]) << 16);
    unsafeAtomicAdd(&out[(size_t)row * D + j + k], val * f);
  }
}

extern "C" void kernel_launch(void* const* d_in, const int* in_sizes, int n_in,
                              void* d_out, int out_size, void* d_ws,
                              size_t ws_size, hipStream_t stream) {
  const float* x        = (const float*)d_in[0];
  const float* edge_val = (const float*)d_in[1];
  const float* W        = (const float*)d_in[2];
  const float* bias     = (const float*)d_in[3];
  const int*   edge_row = (const int*)d_in[4];
  const int*   edge_col = (const int*)d_in[5];
  float* out = (float*)d_out;

  char* ws = (char*)d_ws;
  ushort* support = (ushort*)(ws + SUP_OFF);

  const int gemm_blocks = (N_NODES + MT - 1) / MT;
  gcn_gemm_mfma<<<gemm_blocks, 256, 0, stream>>>(x, W, bias, support, N_NODES);

  if (ws_size >= WS_NEED) {
    int2* recs   = (int2*)(ws + RECS_OFF);
    int*  tails  = (int*)(ws + TAILS_OFF);
    int*  ovfcnt = (int*)(ws + OVFCNT_OFF);
    int3* ovf    = (int3*)(ws + OVF_OFF);

    hipMemsetAsync(tails, 0, (size_t)NB * 4 + 4, stream);
    partition_kernel<<<PBLOCKS, 1024, 0, stream>>>(edge_row, edge_col, edge_val,
                                                   tails, recs, ovfcnt, ovf);
    bucket_gather<<<NB, 256, 0, stream>>>(support, tails, recs, out);
    ovf_apply<<<OVF_CAP * 32 / 256, 256, 0, stream>>>(ovfcnt, ovf, support, out);
  } else {
    hipMemsetAsync(out, 0, (size_t)out_size * sizeof(float), stream);
    const long long spmm_threads = (long long)N_EDGES * 32;
    gcn_spmm_atomic<<<(int)((spmm_threads + 255) / 256), 256, 0, stream>>>(
        support, edge_val, edge_row, edge_col, out);
  }
}